// Round 1
// baseline (375.756 us; speedup 1.0000x reference)
//
#include <hip/hip_runtime.h>

#define LTC_B 512
#define LTC_H 512
#define LTC_I 256

static constexpr float kL2E = 1.4426950408889634f;  // log2(e)

// One pass: for each (b,h), sum_j W[j,h]*sig((v[b,j]-mu[j,h])*sigma[j,h]) * {erev, 1}
// K = reduction length (256 sensory, 512 recurrent).
// RECUR: fuse leak + sensory sums + divide, write v_next. Else write raw sums.
template<int K, bool RECUR>
__global__ __launch_bounds__(512, 2)
void ltc_pass(const float* __restrict__ vsrc,    // B x K
              const float* __restrict__ mu,      // K x H
              const float* __restrict__ sigma,   // K x H
              const float* __restrict__ W,       // K x H
              const float* __restrict__ erev,    // K x H
              float* __restrict__ onum,          // B x H (sensory mode)
              float* __restrict__ oden,          // B x H (sensory mode)
              const float* __restrict__ snum,    // B x H (recur mode)
              const float* __restrict__ sden,    // B x H (recur mode)
              const float* __restrict__ vleak,   // H
              const float* __restrict__ gleak,   // H
              const float* __restrict__ cm,      // H
              float* __restrict__ vout)          // B x H (recur mode)
{
    __shared__ float4 wbuf[32 * 64];   // 32 j-rows x 64 h  (32 KB)
    __shared__ float  vbuf[16][K];     // 16 b-rows x K     (32/16 KB)

    const int tid   = threadIdx.x;
    const int lane  = tid & 63;
    const int wave  = tid >> 6;          // 0..7
    const int hbase = blockIdx.x * 64;
    const int h     = hbase + lane;
    const int bbase = blockIdx.y * 16;

    // Stage the 16 v-rows for this block (coalesced).
    for (int idx = tid; idx < 16 * K; idx += 512) {
        const int bb = idx / K;          // K is a power of two -> shifts
        const int jj = idx - bb * K;
        vbuf[bb][jj] = vsrc[(bbase + bb) * K + jj];
    }

    const int b0 = bbase + wave * 2;     // each wave owns 2 batch rows
    float n0 = 0.f, d0 = 0.f, n1 = 0.f, d1 = 0.f;

    for (int jc = 0; jc < K; jc += 32) {
        __syncthreads();
        // Stage + pre-transform 32 j-rows of weights for this h-tile.
        #pragma unroll
        for (int l = 0; l < 4; ++l) {
            const int idx = tid + l * 512;
            const int jj  = idx >> 6;
            const int hh  = idx & 63;
            const int g   = (jc + jj) * LTC_H + hbase + hh;
            const float sg = sigma[g];
            const float m  = mu[g];
            const float w  = W[g];
            const float ev = erev[g];
            // t = (mu - v)*sigma*log2e = a*v + c ; sig = 1/(1+2^t)
            wbuf[idx] = make_float4(-sg * kL2E, m * sg * kL2E, w * ev, w);
        }
        __syncthreads();

        #pragma unroll
        for (int j = 0; j < 32; ++j) {
            const float4 wv = wbuf[j * 64 + lane];
            const float v0 = vbuf[wave * 2 + 0][jc + j];   // wave-uniform: broadcast
            const float v1 = vbuf[wave * 2 + 1][jc + j];
            const float t0 = fmaf(wv.x, v0, wv.y);
            const float t1 = fmaf(wv.x, v1, wv.y);
            const float e0 = __builtin_amdgcn_exp2f(t0);
            const float e1 = __builtin_amdgcn_exp2f(t1);
            const float s0 = __builtin_amdgcn_rcpf(1.0f + e0);
            const float s1 = __builtin_amdgcn_rcpf(1.0f + e1);
            n0 = fmaf(wv.z, s0, n0);
            d0 = fmaf(wv.w, s0, d0);
            n1 = fmaf(wv.z, s1, n1);
            d1 = fmaf(wv.w, s1, d1);
        }
    }

    if (RECUR) {
        const float vl = vleak[h];
        const float gl = gleak[h];
        const float c  = cm[h];
        const float glvl = gl * vl;
        {
            const float vp  = vbuf[wave * 2 + 0][h];
            const float num = fmaf(c, vp, glvl) + n0 + snum[b0 * LTC_H + h];
            const float den = c + gl + d0 + sden[b0 * LTC_H + h];
            vout[b0 * LTC_H + h] = num * __builtin_amdgcn_rcpf(den + 1e-8f);
        }
        {
            const float vp  = vbuf[wave * 2 + 1][h];
            const float num = fmaf(c, vp, glvl) + n1 + snum[(b0 + 1) * LTC_H + h];
            const float den = c + gl + d1 + sden[(b0 + 1) * LTC_H + h];
            vout[(b0 + 1) * LTC_H + h] = num * __builtin_amdgcn_rcpf(den + 1e-8f);
        }
    } else {
        onum[b0 * LTC_H + h]       = n0;
        oden[b0 * LTC_H + h]       = d0;
        onum[(b0 + 1) * LTC_H + h] = n1;
        oden[(b0 + 1) * LTC_H + h] = d1;
    }
}

extern "C" void kernel_launch(void* const* d_in, const int* in_sizes, int n_in,
                              void* d_out, int out_size, void* d_ws, size_t ws_size,
                              hipStream_t stream) {
    const float* inputs = (const float*)d_in[0];   // B x I
    const float* state  = (const float*)d_in[1];   // B x H
    const float* smu    = (const float*)d_in[2];   // I x H
    const float* ssig   = (const float*)d_in[3];   // I x H
    const float* sW     = (const float*)d_in[4];   // I x H
    const float* serev  = (const float*)d_in[5];   // I x H
    const float* mu     = (const float*)d_in[6];   // H x H
    const float* sig    = (const float*)d_in[7];   // H x H
    const float* W      = (const float*)d_in[8];   // H x H
    const float* erev   = (const float*)d_in[9];   // H x H
    const float* vleak  = (const float*)d_in[10];  // H
    const float* gleak  = (const float*)d_in[11];  // H
    const float* cm     = (const float*)d_in[12];  // H

    float* out  = (float*)d_out;                   // B x H
    float* ws   = (float*)d_ws;
    float* snum = ws;                              // B x H
    float* sden = ws + LTC_B * LTC_H;              // B x H
    float* vA   = ws + 2 * LTC_B * LTC_H;          // B x H ping buffer

    dim3 grid(LTC_H / 64, LTC_B / 16);             // (8, 32) = 256 blocks
    dim3 blk(512);

    // Sensory pass (once): raw sums into ws.
    ltc_pass<LTC_I, false><<<grid, blk, 0, stream>>>(
        inputs, smu, ssig, sW, serev, snum, sden,
        nullptr, nullptr, nullptr, nullptr, nullptr, nullptr);

    // 6 unfolds, ping-ponging so the last lands in d_out.
    const float* vin = state;
    float* targets[6] = {vA, out, vA, out, vA, out};
    for (int s = 0; s < 6; ++s) {
        ltc_pass<LTC_H, true><<<grid, blk, 0, stream>>>(
            vin, mu, sig, W, erev, nullptr, nullptr,
            snum, sden, vleak, gleak, cm, targets[s]);
        vin = targets[s];
    }
}